// Round 4
// baseline (356.886 us; speedup 1.0000x reference)
//
#include <hip/hip_runtime.h>

// RaggedSelectThreshold: keep rows with xs > 0.5, stably compact pl rows to the
// front of an [N,F] buffer (zero-padded), emit new row splits and scatter idxs.
//
// d_out layout (floats): [N*F newfeat][B+1 new_rs][N scatter_idxs]
// d_ws layout (ints):    [N ranks][1024 blk_counts][1024 blk_off][1 n_sel][1 ctr]

#define THRESH 0.5f
#define RPB 1024   // rows per block in pass A (256 threads x 4 rows via float4)

typedef float f4 __attribute__((ext_vector_type(4)));

// Pass A+B fused: per-row encoded prefix ((rank-in-block << 1) | mask) via
// float4 load + shuffle scan; the LAST block to finish also scans the
// per-block counts (last-block pattern, device-scope atomic + threadfence)
// and writes blk_off / n_sel / out_rs.
__global__ void k_count_scan(const float* __restrict__ xs, int N, int nblocks,
                             const int* __restrict__ rs, int nrs,
                             int* __restrict__ ranks, int* __restrict__ blk_counts,
                             unsigned* __restrict__ ctr,
                             int* __restrict__ blk_off, int* __restrict__ nsel_out,
                             float* __restrict__ out_rs) {
    __shared__ int s_wave[4];
    __shared__ int s_flag;
    __shared__ int s_tot;
    __shared__ int s_boff[1024];
    const int tid  = threadIdx.x;
    const int lane = tid & 63, wave = tid >> 6;
    const int idx4 = blockIdx.x * 256 + tid;     // float4 index; rows 4*idx4..+3
    const int row0 = idx4 * 4;

    int m0 = 0, m1 = 0, m2 = 0, m3 = 0;
    if (row0 + 3 < N) {
        f4 v = *reinterpret_cast<const f4*>(&xs[row0]);
        m0 = v.x > THRESH; m1 = v.y > THRESH; m2 = v.z > THRESH; m3 = v.w > THRESH;
    } else if (row0 < N) {                        // ragged tail (N % 4 != 0)
        m0 = xs[row0] > THRESH;
        if (row0 + 1 < N) m1 = xs[row0 + 1] > THRESH;
        if (row0 + 2 < N) m2 = xs[row0 + 2] > THRESH;
    }
    int cnt = m0 + m1 + m2 + m3;

    int inc = cnt;                                // wave-inclusive scan
    #pragma unroll
    for (int d = 1; d < 64; d <<= 1) { int u = __shfl_up(inc, d); if (lane >= d) inc += u; }
    if (lane == 63) s_wave[wave] = inc;
    __syncthreads();
    int waveoff = 0, total = 0;
    #pragma unroll
    for (int w = 0; w < 4; ++w) { int t = s_wave[w]; if (w < wave) waveoff += t; total += t; }
    int pre = waveoff + inc - cnt;                // exclusive prefix within block

    if (row0 + 3 < N) {
        int4 e;
        e.x = (pre << 1) | m0;
        e.y = ((pre + m0) << 1) | m1;
        e.z = ((pre + m0 + m1) << 1) | m2;
        e.w = ((pre + m0 + m1 + m2) << 1) | m3;
        *reinterpret_cast<int4*>(&ranks[row0]) = e;
    } else if (row0 < N) {
        ranks[row0] = (pre << 1) | m0;
        if (row0 + 1 < N) ranks[row0 + 1] = ((pre + m0) << 1) | m1;
        if (row0 + 2 < N) ranks[row0 + 2] = ((pre + m0 + m1) << 1) | m2;
    }

    __syncthreads();          // barrier drains this block's global stores (vmcnt)
    if (tid == 0) {
        blk_counts[blockIdx.x] = total;
        __threadfence();                          // release: publish ranks + count
        unsigned old = atomicAdd(ctr, 1u);        // device-scope by default
        s_flag = (old == (unsigned)(nblocks - 1));
    }
    __syncthreads();
    if (!s_flag) return;

    // ---- last block only: scan blk_counts[0..nblocks) ----
    __threadfence();                              // acquire: see all blocks' writes
    int c[4]; const int base = tid * 4;
    #pragma unroll
    for (int k = 0; k < 4; ++k) c[k] = (base + k < nblocks) ? blk_counts[base + k] : 0;
    int tsum = c[0] + c[1] + c[2] + c[3];
    int tinc = tsum;
    #pragma unroll
    for (int d = 1; d < 64; d <<= 1) { int u = __shfl_up(tinc, d); if (lane >= d) tinc += u; }
    if (lane == 63) s_wave[wave] = tinc;
    __syncthreads();
    int woff = 0, gtot = 0;
    #pragma unroll
    for (int w = 0; w < 4; ++w) { int t = s_wave[w]; if (w < wave) woff += t; gtot += t; }
    int excl = woff + tinc - tsum;
    #pragma unroll
    for (int k = 0; k < 4; ++k) {
        s_boff[base + k] = excl;
        if (base + k < nblocks) blk_off[base + k] = excl;
        excl += c[k];
    }
    if (tid == 0) { nsel_out[0] = gtot; s_tot = gtot; }
    __syncthreads();
    if (tid < nrs) {
        int j = rs[tid];
        int val;
        if (j >= N)      val = s_tot;
        else if (j <= 0) val = 0;
        else             val = s_boff[j >> 10] + (ranks[j] >> 1);
        out_rs[tid] = (float)val;   // int32 written as numeric f32 (exact, <2^24)
    }
}

// Pass C (fused scatter+gather): one 16-lane group per source row i.
//  - selected row i (rank r): out_feat[r] = pl[i]; out_sc[r] = i
//  - slot i >= n_sel: out_feat[i] = 0; out_sc[i] = N
// pl is read-once: nontemporal LOAD keeps 102 MB out of L2.
// Stores go through the normal cache path (NT stores regressed in R2:
// 354.6 vs 343.5 -- the fill kernels prove the normal write path hits 81% peak).
__global__ void k_scatter_gather(const int* __restrict__ ranks,
                                 const int* __restrict__ blk_off,
                                 const int* __restrict__ nsel,
                                 const f4* __restrict__ pl4, int N,
                                 f4* __restrict__ outf4,
                                 float* __restrict__ out_sc) {
    int tid = blockIdx.x * blockDim.x + threadIdx.x;
    int i = tid >> 4;                 // source row
    int c = tid & 15;                 // float4 column within the row (F=64)
    if (i >= N) return;
    const int ns = nsel[0];
    const int e  = ranks[i];
    if (e & 1) {
        int r = blk_off[i >> 10] + (e >> 1);
        f4 v = __builtin_nontemporal_load(&pl4[(size_t)i * 16 + c]);
        outf4[(size_t)r * 16 + c] = v;
        if (c == 0) out_sc[r] = (float)i;
    }
    if (i >= ns) {                    // disjoint slots: r < ns <= i
        f4 z = {0.f, 0.f, 0.f, 0.f};
        outf4[(size_t)i * 16 + c] = z;
        if (c == 0) out_sc[i] = (float)N;
    }
}

extern "C" void kernel_launch(void* const* d_in, const int* in_sizes, int n_in,
                              void* d_out, int out_size, void* d_ws, size_t ws_size,
                              hipStream_t stream) {
    const float* xs = (const float*)d_in[0];
    const float* pl = (const float*)d_in[1];
    const int*   rs = (const int*)d_in[2];
    const int N   = in_sizes[0];        // 800000
    const int F   = in_sizes[1] / N;    // 64 (pass C assumes 64)
    const int nrs = in_sizes[2];        // B+1 = 9

    float* out      = (float*)d_out;
    float* out_feat = out;
    float* out_rs   = out + (size_t)N * F;
    float* out_sc   = out_rs + nrs;

    int* ranks      = (int*)d_ws;
    int* blk_counts = ranks + N;
    int* blk_off    = blk_counts + 1024;
    int* nsel       = blk_off + 1024;
    unsigned* ctr   = (unsigned*)(nsel + 1);

    const int nblocks = (N + RPB - 1) / RPB;   // 782 (must be <= 1024)

    hipMemsetAsync(ctr, 0, sizeof(unsigned), stream);   // poisoned ws -> zero the counter

    k_count_scan<<<nblocks, 256, 0, stream>>>(xs, N, nblocks, rs, nrs,
                                              ranks, blk_counts, ctr,
                                              blk_off, nsel, out_rs);
    k_scatter_gather<<<(N * 16 + 255) / 256, 256, 0, stream>>>(
        ranks, blk_off, nsel, (const f4*)pl, N, (f4*)out_feat, out_sc);
}

// Round 5
// 343.048 us; speedup vs baseline: 1.0403x; 1.0403x over previous
//
#include <hip/hip_runtime.h>

// RaggedSelectThreshold: keep rows with xs > 0.5, stably compact pl rows to the
// front of an [N,F] buffer (zero-padded), emit new row splits and scatter idxs.
// All outputs written as float32 values (harness reads d_out as one f32 blob).
//
// d_out layout (floats): [N*F newfeat][B+1 new_rs][N scatter_idxs]
// d_ws layout (ints):    [N ranks][1024 blk_counts][1024 blk_off][1 n_sel]
//
// Session history (measured):
//   R0 4-pass: 343.3 us | R1 3-pass (this): 343.5 us
//   R2/R4 2-pass last-block-scan (+/- NT stores): 354.6 / 356.9 us  <- fences cost
// Floor: ~255 us harness poison fills (2x 832 MB @ 81% peak, from rocprof)
//        + ~55-60 us mandatory traffic (313 MB) + launch/latency overhead.

#define THRESH 0.5f
#define RPB 1024   // rows per block in pass A (4 chunks of 256 threads)

// Pass A: per-row encoded prefix: (count of selected rows in [blk_start, i) << 1) | mask
__global__ void k_count(const float* __restrict__ xs, int N,
                        int* __restrict__ ranks, int* __restrict__ blk_counts) {
    __shared__ int wc[4][4];                     // [chunk][wave]
    const int tid  = threadIdx.x;
    const int lane = tid & 63, wave = tid >> 6;
    const int base = blockIdx.x * RPB;
    int running = 0;
    for (int c = 0; c < 4; ++c) {
        int i = base + c * 256 + tid;
        int m = (i < N) && (xs[i] > THRESH);
        unsigned long long bal = __ballot(m);
        if (lane == 0) wc[c][wave] = __popcll(bal);
        __syncthreads();
        int waveoff = 0, tot = 0;
        for (int w = 0; w < 4; ++w) { int v = wc[c][w]; if (w < wave) waveoff += v; tot += v; }
        int pre = running + waveoff + (int)__popcll(bal & ((1ull << lane) - 1ull));
        if (i < N) ranks[i] = (pre << 1) | m;
        running += tot;
    }
    if (tid == 0) blk_counts[blockIdx.x] = running;
}

// Pass B: scan block counts (nblocks <= 1024), write offsets + n_sel + new_rs.
__global__ void k_scan(const int* __restrict__ blk_counts, int nblocks,
                       const int* __restrict__ ranks,
                       const int* __restrict__ rs, int nrs, int N,
                       int* __restrict__ blk_off, int* __restrict__ nsel_out,
                       float* __restrict__ out_rs) {
    __shared__ int s[1024];
    __shared__ int s_total;
    const int t = threadIdx.x;
    int v = (t < nblocks) ? blk_counts[t] : 0;
    s[t] = v;
    __syncthreads();
    // Hillis-Steele inclusive scan over 1024 entries
    for (int d = 1; d < 1024; d <<= 1) {
        int add = (t >= d) ? s[t - d] : 0;
        __syncthreads();
        s[t] += add;
        __syncthreads();
    }
    int excl = s[t] - v;
    if (t < nblocks) blk_off[t] = excl;
    if (t == 1023) s_total = s[t];
    __syncthreads();                 // also makes blk_off global writes visible in-block
    int n_sel = s_total;
    if (t == 0) nsel_out[0] = n_sel;
    if (t < nrs) {
        int j = rs[t];
        int val;
        if (j >= N)      val = n_sel;
        else if (j <= 0) val = 0;
        else             val = blk_off[j >> 10] + (ranks[j] >> 1);
        out_rs[t] = (float)val;      // int32 output written as numeric f32 (exact, <2^24)
    }
}

// Pass C (fused scatter+gather): one 16-lane group per source row i.
//  - selected row i (rank r): out_feat[r] = pl[i]; out_sc[r] = i
//  - slot i >= n_sel: out_feat[i] = 0; out_sc[i] = N
// Both writes can fire for one i (they target disjoint slots: r < n_sel <= i).
// ranks/blk_off reads are same-address broadcast within the 16-lane group.
__global__ void k_scatter_gather(const int* __restrict__ ranks,
                                 const int* __restrict__ blk_off,
                                 const int* __restrict__ nsel,
                                 const float4* __restrict__ pl4, int N,
                                 float4* __restrict__ outf4,
                                 float* __restrict__ out_sc) {
    int tid = blockIdx.x * blockDim.x + threadIdx.x;
    int i = tid >> 4;                 // source row
    int c = tid & 15;                 // float4 column within the row (F=64)
    if (i >= N) return;
    const int ns = nsel[0];
    const int e  = ranks[i];
    if (e & 1) {
        int r = blk_off[i >> 10] + (e >> 1);
        float4 v = pl4[(size_t)i * 16 + c];
        outf4[(size_t)r * 16 + c] = v;
        if (c == 0) out_sc[r] = (float)i;
    }
    if (i >= ns) {
        outf4[(size_t)i * 16 + c] = make_float4(0.f, 0.f, 0.f, 0.f);
        if (c == 0) out_sc[i] = (float)N;
    }
}

extern "C" void kernel_launch(void* const* d_in, const int* in_sizes, int n_in,
                              void* d_out, int out_size, void* d_ws, size_t ws_size,
                              hipStream_t stream) {
    const float* xs = (const float*)d_in[0];
    const float* pl = (const float*)d_in[1];
    const int*   rs = (const int*)d_in[2];
    const int N   = in_sizes[0];        // 800000
    const int F   = in_sizes[1] / N;    // 64 (kernel C assumes 64)
    const int nrs = in_sizes[2];        // B+1 = 9

    float* out      = (float*)d_out;
    float* out_feat = out;
    float* out_rs   = out + (size_t)N * F;
    float* out_sc   = out_rs + nrs;

    int* ranks      = (int*)d_ws;
    int* blk_counts = ranks + N;
    int* blk_off    = blk_counts + 1024;
    int* nsel       = blk_off + 1024;

    const int nblocks = (N + RPB - 1) / RPB;   // 782 (must be <= 1024)

    k_count<<<nblocks, 256, 0, stream>>>(xs, N, ranks, blk_counts);
    k_scan <<<1,       1024, 0, stream>>>(blk_counts, nblocks, ranks, rs, nrs, N,
                                          blk_off, nsel, out_rs);
    k_scatter_gather<<<(N * 16 + 255) / 256, 256, 0, stream>>>(
        ranks, blk_off, nsel, (const float4*)pl, N, (float4*)out_feat, out_sc);
}

// Round 6
// 341.662 us; speedup vs baseline: 1.0446x; 1.0041x over previous
//
#include <hip/hip_runtime.h>

// RaggedSelectThreshold: keep rows with xs > 0.5, stably compact pl rows to the
// front of an [N,F] buffer (zero-padded), emit new row splits and scatter idxs.
// All outputs written as float32 values (harness reads d_out as one f32 blob).
//
// d_out layout (floats): [N*F newfeat][B+1 new_rs][N scatter_idxs]
// d_ws layout (ints):    [N ranks][1024 blk_counts][1024 blk_off][1 n_sel]
//
// Session history (measured):
//   R0 4-pass: 343.3 | R1/R5 3-pass: 343.5 / 343.0   <- best structure
//   R2/R4 2-pass last-block-scan: 354.6 / 356.9      <- device-scope fences cost
// This round: pass B 1024-thr Hillis-Steele (20 barriers) -> 256-thr shuffle
// scan (2 barriers). Everything else byte-identical to the 343.0 kernel.

#define THRESH 0.5f
#define RPB 1024   // rows per block in pass A (4 chunks of 256 threads)

// Pass A: per-row encoded prefix: (count of selected rows in [blk_start, i) << 1) | mask
__global__ void k_count(const float* __restrict__ xs, int N,
                        int* __restrict__ ranks, int* __restrict__ blk_counts) {
    __shared__ int wc[4][4];                     // [chunk][wave]
    const int tid  = threadIdx.x;
    const int lane = tid & 63, wave = tid >> 6;
    const int base = blockIdx.x * RPB;
    int running = 0;
    for (int c = 0; c < 4; ++c) {
        int i = base + c * 256 + tid;
        int m = (i < N) && (xs[i] > THRESH);
        unsigned long long bal = __ballot(m);
        if (lane == 0) wc[c][wave] = __popcll(bal);
        __syncthreads();
        int waveoff = 0, tot = 0;
        for (int w = 0; w < 4; ++w) { int v = wc[c][w]; if (w < wave) waveoff += v; tot += v; }
        int pre = running + waveoff + (int)__popcll(bal & ((1ull << lane) - 1ull));
        if (i < N) ranks[i] = (pre << 1) | m;
        running += tot;
    }
    if (tid == 0) blk_counts[blockIdx.x] = running;
}

// Pass B: scan block counts (nblocks <= 1024) with 256 threads, 4 counts each,
// wave shuffle scan + 2 barriers (replaces 1024-thr Hillis-Steele, 20 barriers).
// Same math as the R2/R4 last-block scan (correctness-proven), minus the fences.
__global__ void k_scan(const int* __restrict__ blk_counts, int nblocks,
                       const int* __restrict__ ranks,
                       const int* __restrict__ rs, int nrs, int N,
                       int* __restrict__ blk_off, int* __restrict__ nsel_out,
                       float* __restrict__ out_rs) {
    __shared__ int s_wave[4];
    __shared__ int s_boff[1024];
    __shared__ int s_tot;
    const int tid  = threadIdx.x;                // 0..255
    const int lane = tid & 63, wave = tid >> 6;
    const int base = tid * 4;
    int c[4];
    #pragma unroll
    for (int k = 0; k < 4; ++k) c[k] = (base + k < nblocks) ? blk_counts[base + k] : 0;
    int tsum = c[0] + c[1] + c[2] + c[3];
    int tinc = tsum;                              // wave-inclusive scan of per-thread sums
    #pragma unroll
    for (int d = 1; d < 64; d <<= 1) { int u = __shfl_up(tinc, d); if (lane >= d) tinc += u; }
    if (lane == 63) s_wave[wave] = tinc;
    __syncthreads();
    int woff = 0, gtot = 0;
    #pragma unroll
    for (int w = 0; w < 4; ++w) { int t = s_wave[w]; if (w < wave) woff += t; gtot += t; }
    int excl = woff + tinc - tsum;                // exclusive prefix of this thread's 4
    #pragma unroll
    for (int k = 0; k < 4; ++k) {
        s_boff[base + k] = excl;
        if (base + k < nblocks) blk_off[base + k] = excl;
        excl += c[k];
    }
    if (tid == 0) { nsel_out[0] = gtot; s_tot = gtot; }
    __syncthreads();
    if (tid < nrs) {
        int j = rs[tid];
        int val;
        if (j >= N)      val = s_tot;
        else if (j <= 0) val = 0;
        else             val = s_boff[j >> 10] + (ranks[j] >> 1);
        out_rs[tid] = (float)val;    // int32 output written as numeric f32 (exact, <2^24)
    }
}

// Pass C (fused scatter+gather): one 16-lane group per source row i.
//  - selected row i (rank r): out_feat[r] = pl[i]; out_sc[r] = i
//  - slot i >= n_sel: out_feat[i] = 0; out_sc[i] = N
// Both writes can fire for one i (they target disjoint slots: r < n_sel <= i).
// ranks/blk_off reads are same-address broadcast within the 16-lane group.
__global__ void k_scatter_gather(const int* __restrict__ ranks,
                                 const int* __restrict__ blk_off,
                                 const int* __restrict__ nsel,
                                 const float4* __restrict__ pl4, int N,
                                 float4* __restrict__ outf4,
                                 float* __restrict__ out_sc) {
    int tid = blockIdx.x * blockDim.x + threadIdx.x;
    int i = tid >> 4;                 // source row
    int c = tid & 15;                 // float4 column within the row (F=64)
    if (i >= N) return;
    const int ns = nsel[0];
    const int e  = ranks[i];
    if (e & 1) {
        int r = blk_off[i >> 10] + (e >> 1);
        float4 v = pl4[(size_t)i * 16 + c];
        outf4[(size_t)r * 16 + c] = v;
        if (c == 0) out_sc[r] = (float)i;
    }
    if (i >= ns) {
        outf4[(size_t)i * 16 + c] = make_float4(0.f, 0.f, 0.f, 0.f);
        if (c == 0) out_sc[i] = (float)N;
    }
}

extern "C" void kernel_launch(void* const* d_in, const int* in_sizes, int n_in,
                              void* d_out, int out_size, void* d_ws, size_t ws_size,
                              hipStream_t stream) {
    const float* xs = (const float*)d_in[0];
    const float* pl = (const float*)d_in[1];
    const int*   rs = (const int*)d_in[2];
    const int N   = in_sizes[0];        // 800000
    const int F   = in_sizes[1] / N;    // 64 (kernel C assumes 64)
    const int nrs = in_sizes[2];        // B+1 = 9

    float* out      = (float*)d_out;
    float* out_feat = out;
    float* out_rs   = out + (size_t)N * F;
    float* out_sc   = out_rs + nrs;

    int* ranks      = (int*)d_ws;
    int* blk_counts = ranks + N;
    int* blk_off    = blk_counts + 1024;
    int* nsel       = blk_off + 1024;

    const int nblocks = (N + RPB - 1) / RPB;   // 782 (must be <= 1024)

    k_count<<<nblocks, 256, 0, stream>>>(xs, N, ranks, blk_counts);
    k_scan <<<1,       256, 0, stream>>>(blk_counts, nblocks, ranks, rs, nrs, N,
                                         blk_off, nsel, out_rs);
    k_scatter_gather<<<(N * 16 + 255) / 256, 256, 0, stream>>>(
        ranks, blk_off, nsel, (const float4*)pl, N, (float4*)out_feat, out_sc);
}